// Round 1
// baseline (161.629 us; speedup 1.0000x reference)
//
#include <hip/hip_runtime.h>
#include <hip/hip_bf16.h>
#include <stdint.h>

typedef __bf16 bf16;
typedef bf16 bf16x8 __attribute__((ext_vector_type(8)));
typedef bf16 bf16x4 __attribute__((ext_vector_type(4)));
typedef float f32x4 __attribute__((ext_vector_type(4)));

#define MFMA_16x16x32(a, b, c) __builtin_amdgcn_mfma_f32_16x16x32_bf16((a), (b), (c), 0, 0, 0)

// ---- problem sizes ----
constexpr int B = 16, S = 512, H = 768, NH = 12, DH = 64;
constexpr long NHID = (long)B * S * H;          // 6291456
constexpr long NW = (long)8 * H * H;            // 4718592 per weight tensor

// ---- workspace layout (bytes) ----
constexpr size_t XB_OFF = 0;
constexpr size_t XB_SZ  = (size_t)NHID * 2;
constexpr size_t W_SZ   = (size_t)NW * 2;
constexpr size_t WQ_OFF = XB_OFF + XB_SZ;
constexpr size_t WK_OFF = WQ_OFF + W_SZ;
constexpr size_t WV_OFF = WK_OFF + W_SZ;
constexpr size_t PROJ_SZ = (size_t)B * NH * S * DH * 2;  // 12582912
constexpr size_t QB_OFF = WV_OFF + W_SZ;
constexpr size_t KB_OFF = QB_OFF + PROJ_SZ;
constexpr size_t VB_OFF = KB_OFF + PROJ_SZ;
constexpr size_t WS_NEED = VB_OFF + PROJ_SZ;    // 78643200 (~75 MB)

// ---------------- f32 -> bf16 convert (vectorized) ----------------
__global__ void cvt_f32_bf16(const float* __restrict__ src, bf16* __restrict__ dst, long n) {
  long i = ((long)blockIdx.x * blockDim.x + threadIdx.x) * 8;
  if (i >= n) return;
  const float4* sp = reinterpret_cast<const float4*>(src + i);
  float4 a = sp[0], b = sp[1];
  bf16x8 o;
  o[0] = (bf16)a.x; o[1] = (bf16)a.y; o[2] = (bf16)a.z; o[3] = (bf16)a.w;
  o[4] = (bf16)b.x; o[5] = (bf16)b.y; o[6] = (bf16)b.z; o[7] = (bf16)b.w;
  *reinterpret_cast<bf16x8*>(dst + i) = o;
}

// ---------------- projection GEMM ----------------
// grid: (4 m-tiles, 18 n-tiles [q|k|v], 16 batches), 256 threads.
// C[m=512, n=768] = X[512,768] @ W[e]^T (+bias), W row-major [out][in].
__global__ __launch_bounds__(256, 3) void proj_gemm(
    const bf16* __restrict__ Xb,
    const bf16* __restrict__ Wqb, const bf16* __restrict__ Wkb, const bf16* __restrict__ Wvb,
    const float* __restrict__ bq, const float* __restrict__ bk, const float* __restrict__ bv,
    const int* __restrict__ eidx,
    bf16* __restrict__ Qb, bf16* __restrict__ Kb, bf16* __restrict__ Vb)
{
  __shared__ __align__(16) bf16 As[128 * 32];
  __shared__ __align__(16) bf16 Bs[128 * 32];

  const int b = blockIdx.z;
  const int m0 = blockIdx.x * 128;
  const int gy = blockIdx.y;
  const int proj = gy / 6;
  const int n0 = (gy % 6) * 128;
  const int e = eidx[b];

  const bf16* W = (proj == 0 ? Wqb : (proj == 1 ? Wkb : Wvb)) + (size_t)e * H * H;
  const float* bias = (proj == 0 ? bq : (proj == 1 ? bk : bv)) + (size_t)e * H;
  bf16* Out = (proj == 0 ? Qb : (proj == 1 ? Kb : Vb));

  const int tid = threadIdx.x;
  const int lane = tid & 63;
  const int wave = tid >> 6;
  const int wm = wave >> 1, wn = wave & 1;
  const int r = lane & 15, lg = lane >> 4;

  const bf16* Abase = Xb + ((size_t)b * S + m0) * H;
  const bf16* Bbase = W + (size_t)n0 * H;

  const int srow = lane >> 2;        // 0..15 within segment
  const int skc = (lane & 3) * 8;    // k element offset (16B chunks)

  f32x4 acc[4][4] = {};

#pragma unroll 1
  for (int kt = 0; kt < 24; ++kt) {
    const int k0 = kt * 32;
    __syncthreads();
#pragma unroll
    for (int i = 0; i < 2; ++i) {
      const int seg = i * 4 + wave;                         // 0..7 -> 16 rows each
      const bf16* ga = Abase + (size_t)(seg * 16 + srow) * H + k0 + skc;
      const bf16* gb = Bbase + (size_t)(seg * 16 + srow) * H + k0 + skc;
      __builtin_amdgcn_global_load_lds(
          (const __attribute__((address_space(1))) void*)ga,
          (__attribute__((address_space(3))) void*)(As + seg * 512), 16, 0, 0);
      __builtin_amdgcn_global_load_lds(
          (const __attribute__((address_space(1))) void*)gb,
          (__attribute__((address_space(3))) void*)(Bs + seg * 512), 16, 0, 0);
    }
    __syncthreads();

    bf16x8 af[4], bfr[4];
#pragma unroll
    for (int mi = 0; mi < 4; ++mi)
      af[mi] = *reinterpret_cast<const bf16x8*>(&As[(wm * 64 + mi * 16 + r) * 32 + lg * 8]);
#pragma unroll
    for (int ni = 0; ni < 4; ++ni)
      bfr[ni] = *reinterpret_cast<const bf16x8*>(&Bs[(wn * 64 + ni * 16 + r) * 32 + lg * 8]);
#pragma unroll
    for (int mi = 0; mi < 4; ++mi)
#pragma unroll
      for (int ni = 0; ni < 4; ++ni)
        acc[mi][ni] = MFMA_16x16x32(af[mi], bfr[ni], acc[mi][ni]);
  }

  // epilogue: bias add, cast bf16, scatter into [B,NH,S,DH]
#pragma unroll
  for (int ni = 0; ni < 4; ++ni) {
    const int col = n0 + wn * 64 + ni * 16 + r;   // 0..767 within this projection
    const int nh = col >> 6, dh = col & 63;
    const float bb = bias[col];
    bf16* orow = Out + ((size_t)b * NH + nh) * S * DH + dh;
#pragma unroll
    for (int mi = 0; mi < 4; ++mi) {
#pragma unroll
      for (int rr = 0; rr < 4; ++rr) {
        const int srow2 = m0 + wm * 64 + mi * 16 + lg * 4 + rr;
        orow[(size_t)srow2 * DH] = (bf16)(acc[mi][ni][rr] + bb);
      }
    }
  }
}

// ---------------- fused attention ----------------
// grid.x = 192 heads * 8 q-blocks; 256 threads = 4 waves, 16 q-rows per wave.
// Swapped QK^T: S^T[k][q] = sum_d K[k][d] * Q[q][d]; each lane owns one q.
__global__ __launch_bounds__(256, 2) void attn_kernel(
    const bf16* __restrict__ Qb, const bf16* __restrict__ Kb, const bf16* __restrict__ Vb,
    const float* __restrict__ mask, float* __restrict__ out)
{
  __shared__ __align__(16) bf16 Vt[64][520];   // V^T, padded: stride 1040B
  __shared__ float maskS[512];

  const int bh = blockIdx.x >> 3;              // b*NH + h
  const int b = bh / NH;
  const int h = bh % NH;
  const int tid = threadIdx.x;
  const int wave = tid >> 6;
  const int lane = tid & 63;
  const int r = lane & 15, lg = lane >> 4;
  const int q0 = ((blockIdx.x & 7) * 4 + wave) * 16;

  const bf16* Q = Qb + (size_t)bh * S * DH;
  const bf16* K = Kb + (size_t)bh * S * DH;
  const bf16* V = Vb + (size_t)bh * S * DH;

  for (int i = tid; i < S; i += 256) maskS[i] = mask[b * S + i];
#pragma unroll 1
  for (int c = tid; c < S * 8; c += 256) {     // transpose-stage V into LDS
    const int k = c & (S - 1);
    const int d0 = (c >> 9) * 8;
    bf16x8 v = *reinterpret_cast<const bf16x8*>(&V[(size_t)k * DH + d0]);
#pragma unroll
    for (int j = 0; j < 8; ++j) Vt[d0 + j][k] = v[j];
  }
  __syncthreads();

  // hoisted Q fragments (this wave's 16 q-rows)
  bf16x8 qf0 = *reinterpret_cast<const bf16x8*>(&Q[(size_t)(q0 + r) * DH + lg * 8]);
  bf16x8 qf1 = *reinterpret_cast<const bf16x8*>(&Q[(size_t)(q0 + r) * DH + 32 + lg * 8]);

  // QK^T (swapped): 32 k-tiles of 16, K=64 in two MFMA steps
  f32x4 sa[32];
#pragma unroll
  for (int t = 0; t < 32; ++t) {
    const bf16* Kr = K + (size_t)(t * 16 + r) * DH;
    bf16x8 kf0 = *reinterpret_cast<const bf16x8*>(Kr + lg * 8);
    bf16x8 kf1 = *reinterpret_cast<const bf16x8*>(Kr + 32 + lg * 8);
    f32x4 a = {};
    a = MFMA_16x16x32(kf0, qf0, a);
    a = MFMA_16x16x32(kf1, qf1, a);
    sa[t] = a;
  }

  // softmax over k for lane's q (=q0+r): 128 local values + 2 shuffles
  float mx = -3.0e38f;
#pragma unroll
  for (int t = 0; t < 32; ++t)
#pragma unroll
    for (int rr = 0; rr < 4; ++rr) {
      float s = sa[t][rr] * 0.125f + maskS[t * 16 + lg * 4 + rr];
      sa[t][rr] = s;
      mx = fmaxf(mx, s);
    }
  mx = fmaxf(mx, __shfl_xor(mx, 16));
  mx = fmaxf(mx, __shfl_xor(mx, 32));
  float sum = 0.f;
#pragma unroll
  for (int t = 0; t < 32; ++t)
#pragma unroll
    for (int rr = 0; rr < 4; ++rr) {
      float p = __expf(sa[t][rr] - mx);
      sa[t][rr] = p;
      sum += p;
    }
  sum += __shfl_xor(sum, 16);
  sum += __shfl_xor(sum, 32);
  const float inv = 1.0f / sum;

  // PV: ctx^T[d][q] = sum_k V^T[d][k] * P^T[k][q]
  // P-fragment comes free from accumulator layout; V^T read with SAME k-bijection:
  // k = kc*32 + (j>>2)*16 + lg*4 + (j&3)
  f32x4 ctx[4] = {};
#pragma unroll
  for (int kc = 0; kc < 16; ++kc) {
    bf16x8 pf;
    f32x4 p0 = sa[2 * kc], p1 = sa[2 * kc + 1];
    pf[0] = (bf16)p0[0]; pf[1] = (bf16)p0[1]; pf[2] = (bf16)p0[2]; pf[3] = (bf16)p0[3];
    pf[4] = (bf16)p1[0]; pf[5] = (bf16)p1[1]; pf[6] = (bf16)p1[2]; pf[7] = (bf16)p1[3];
    const int kb = kc * 32 + lg * 4;
#pragma unroll
    for (int dt = 0; dt < 4; ++dt) {
      const bf16* vr = &Vt[dt * 16 + r][kb];
      bf16x4 lo = *reinterpret_cast<const bf16x4*>(vr);
      bf16x4 hi = *reinterpret_cast<const bf16x4*>(vr + 16);
      bf16x8 vf;
      vf[0] = lo[0]; vf[1] = lo[1]; vf[2] = lo[2]; vf[3] = lo[3];
      vf[4] = hi[0]; vf[5] = hi[1]; vf[6] = hi[2]; vf[7] = hi[3];
      ctx[dt] = MFMA_16x16x32(vf, pf, ctx[dt]);
    }
  }

  // write ctx (f32): lane's q = q0+r, d = dt*16 + lg*4 + rr
  float* obase = out + ((size_t)b * S + q0 + r) * H + h * DH;
#pragma unroll
  for (int dt = 0; dt < 4; ++dt)
#pragma unroll
    for (int rr = 0; rr < 4; ++rr)
      obase[dt * 16 + lg * 4 + rr] = ctx[dt][rr] * inv;
}

extern "C" void kernel_launch(void* const* d_in, const int* in_sizes, int n_in,
                              void* d_out, int out_size, void* d_ws, size_t ws_size,
                              hipStream_t stream) {
  const float* hidden = (const float*)d_in[0];
  const float* mask   = (const float*)d_in[1];
  const float* Wq = (const float*)d_in[2];
  const float* bq = (const float*)d_in[3];
  const float* Wk = (const float*)d_in[4];
  const float* bk = (const float*)d_in[5];
  const float* Wv = (const float*)d_in[6];
  const float* bv = (const float*)d_in[7];
  const int* eidx = (const int*)d_in[8];

  if (ws_size < WS_NEED) return;

  char* ws = (char*)d_ws;
  bf16* Xb  = (bf16*)(ws + XB_OFF);
  bf16* Wqb = (bf16*)(ws + WQ_OFF);
  bf16* Wkb = (bf16*)(ws + WK_OFF);
  bf16* Wvb = (bf16*)(ws + WV_OFF);
  bf16* Qbf = (bf16*)(ws + QB_OFF);
  bf16* Kbf = (bf16*)(ws + KB_OFF);
  bf16* Vbf = (bf16*)(ws + VB_OFF);
  float* out = (float*)d_out;

  cvt_f32_bf16<<<3072, 256, 0, stream>>>(hidden, Xb, NHID);
  cvt_f32_bf16<<<2304, 256, 0, stream>>>(Wq, Wqb, NW);
  cvt_f32_bf16<<<2304, 256, 0, stream>>>(Wk, Wkb, NW);
  cvt_f32_bf16<<<2304, 256, 0, stream>>>(Wv, Wvb, NW);
  proj_gemm<<<dim3(4, 18, 16), 256, 0, stream>>>(Xb, Wqb, Wkb, Wvb, bq, bk, bv, eidx,
                                                 Qbf, Kbf, Vbf);
  attn_kernel<<<1536, 256, 0, stream>>>(Qbf, Kbf, Vbf, mask, out);
}